// Round 21
// baseline (125.721 us; speedup 1.0000x reference)
//
#include <hip/hip_runtime.h>
#include <stdint.h>

typedef short s16x8 __attribute__((ext_vector_type(8)));
typedef float f32x4 __attribute__((ext_vector_type(4)));
typedef unsigned int u32x4 __attribute__((ext_vector_type(4)));

#define AS1 __attribute__((address_space(1)))
#define AS3 __attribute__((address_space(3)))

static constexpr int Bc = 2, Tc = 2048, NXc = 1024, Hc = 16;
static constexpr float NEGC = -1e9f;
static constexpr float L2E = 1.44269504088896340736f;  // log2(e)
static constexpr float LN2 = 0.69314718055994530942f;  // 1/log2(e)

static __device__ __forceinline__ unsigned short f2bf(float f) {
  uint32_t u = __builtin_bit_cast(uint32_t, f);
  u += 0x7fffu + ((u >> 16) & 1u);
  return (unsigned short)(u >> 16);
}

static __device__ __forceinline__ float exp2fast(float x) {
  return __builtin_amdgcn_exp2f(x);  // v_exp_f32: D = 2^S0
}

static __device__ __forceinline__ uint32_t cvt_pk_bf16(float lo, float hi) {
  uint32_t r;
  asm("v_cvt_pk_bf16_f32 %0, %1, %2" : "=v"(r) : "v"(lo), "v"(hi));
  return r;
}

static __device__ __forceinline__ void gload_lds16(const void* g, void* l) {
  __builtin_amdgcn_global_load_lds((const AS1 uint32_t*)g, (AS3 uint32_t*)l, 16, 0, 0);
}

// ---------------- fused prep: cvt_x | 3 transposes | tilemask(64x64) ----------------
__global__ __launch_bounds__(256) void k_prep(
    const float* __restrict__ x, unsigned short* __restrict__ xb,
    const float* __restrict__ w_attn, unsigned short* __restrict__ wattnT,
    const float* __restrict__ w_proj, const float* __restrict__ w_proj1,
    unsigned short* __restrict__ wcatT,
    const float* __restrict__ adj, unsigned char* __restrict__ tm) {
  __shared__ float tile[32][33];
  __shared__ int s_any, s_all;
  const int bid = blockIdx.x;
  const int t = threadIdx.x;

  if (bid < 4096) {  // x -> bf16
    int i = bid * 256 + t;
    float4 v = ((const float4*)x)[i];
    uint32_t lo = (uint32_t)f2bf(v.x) | ((uint32_t)f2bf(v.y) << 16);
    uint32_t hi = (uint32_t)f2bf(v.z) | ((uint32_t)f2bf(v.w) << 16);
    ((uint2*)xb)[i] = make_uint2(lo, hi);
    return;
  }
  if (bid < 9216) {  // f32 [K][N] -> bf16 [N][dld] transposes
    const float* src; unsigned short* dst;
    int scols, dld, dkoff, n0, k0; float scale;
    if (bid < 7168) {
      int b = bid - 4096; n0 = (b % 96) * 32; k0 = (b / 96) * 32;
      src = w_attn; scols = 3072; dst = wattnT; dld = 1024; dkoff = 0; scale = 1.0f;
    } else if (bid < 8192) {
      int b = bid - 7168; n0 = (b & 31) * 32; k0 = (b >> 5) * 32;
      src = w_proj; scols = 1024; dst = wcatT; dld = 2048; dkoff = 0; scale = 1.0f;
    } else {
      int b = bid - 8192; n0 = (b & 31) * 32; k0 = (b >> 5) * 32;
      // w_proj1 pre-scaled by ln2 cancels the log2e baked into q (exp2 rebasing)
      src = w_proj1; scols = 1024; dst = wcatT; dld = 2048; dkoff = 1024; scale = LN2;
    }
    int tx = t & 31, ty = t >> 5;
#pragma unroll
    for (int r = 0; r < 4; r++)
      tile[ty + r * 8][tx] = src[(size_t)(k0 + ty + r * 8) * scols + n0 + tx];
    __syncthreads();
#pragma unroll
    for (int r = 0; r < 4; r++) {
      int n = n0 + ty + r * 8;
      dst[(size_t)n * dld + dkoff + k0 + tx] = f2bf(tile[tx][ty + r * 8] * scale);
    }
    return;
  }
  {  // adjacency 64x64 tile classifier: 0=skip, 1=mixed, 2=all-ones
    int b = bid - 9216;
    int kt = b & 31, qt = b >> 5;
    bool anyv = false, all1 = true;
#pragma unroll
    for (int i = 0; i < 4; i++) {
      int e = t * 4 + i;
      int row = e >> 4, c4 = e & 15;
      float4 v = *(const float4*)&adj[(size_t)(qt * 64 + row) * Tc + kt * 64 + c4 * 4];
      anyv |= (v.x != 0.f) | (v.y != 0.f) | (v.z != 0.f) | (v.w != 0.f);
      all1 &= (v.x == 1.f) & (v.y == 1.f) & (v.z == 1.f) & (v.w == 1.f);
    }
    if (t == 0) { s_any = 0; s_all = 1; }
    __syncthreads();
    if (anyv) s_any = 1;
    if (!all1) s_all = 0;
    __syncthreads();
    if (t == 0) tm[qt * 32 + kt] = (unsigned char)(s_any ? (s_all ? 2 : 1) : 0);
  }
}

// ---------------- GEMM0: qkv = xb @ wattnT^T + b_attn (single-barrier dbuf, r19) -----
__global__ __launch_bounds__(256) void k_gemm0(
    const unsigned short* __restrict__ A, int lda,
    const unsigned short* __restrict__ BT, int K,
    const float* __restrict__ bias0, unsigned short* __restrict__ Cb) {
  __shared__ __align__(16) unsigned short As[2][128 * 32];
  __shared__ __align__(16) unsigned short Bs[2][128 * 32];
  const int nbx = gridDim.x, nby = gridDim.y;
  const int nwg = nbx * nby;
  int id = blockIdx.y * nbx + blockIdx.x;
  id = (id & 7) * (nwg >> 3) + (id >> 3);  // T1 XCD swizzle (nwg % 8 == 0)
  const int bx = id % nbx;
  const int by = id / nbx;
  const int m0 = by * 128;
  const int n0 = bx * 128;

  const int lane = threadIdx.x & 63;
  const int w = threadIdx.x >> 6;
  const int wr = (w >> 1) * 64;
  const int wc = (w & 1) * 64;
  const int g = lane >> 4, lr = lane & 15;
  const int srow = lane >> 2;
  const int scol = lane & 3;
  f32x4 acc[4][4] = {};

  auto stage = [&](int k0, int buf) {
#pragma unroll
    for (int i = 0; i < 2; i++) {
      int c = w * 2 + i;
      int row = c * 16 + srow;
      int cs = scol ^ (row & 3);
      gload_lds16(A + (size_t)(m0 + row) * lda + k0 + cs * 8, (void*)(&As[buf][0] + c * 512));
      gload_lds16(BT + (size_t)(n0 + row) * K + k0 + cs * 8, (void*)(&Bs[buf][0] + c * 512));
    }
  };

  stage(0, 0);
  __syncthreads();

  for (int k0 = 0; k0 < K; k0 += 32) {
    const int cur = (k0 >> 5) & 1;
    if (k0 + 32 < K) stage(k0 + 32, cur ^ 1);  // issue-early: drained at the barrier
    s16x8 af[4], bfr[4];
#pragma unroll
    for (int m = 0; m < 4; m++) {
      int row = wr + m * 16 + lr;
      af[m] = *(const s16x8*)((const char*)&As[cur][0] + row * 64 + ((g ^ (row & 3)) * 16));
    }
#pragma unroll
    for (int n = 0; n < 4; n++) {
      int row = wc + n * 16 + lr;
      bfr[n] = *(const s16x8*)((const char*)&Bs[cur][0] + row * 64 + ((g ^ (row & 3)) * 16));
    }
#pragma unroll
    for (int m = 0; m < 4; m++)
#pragma unroll
      for (int n = 0; n < 4; n++)
        acc[m][n] = __builtin_amdgcn_mfma_f32_16x16x32_bf16(af[m], bfr[n], acc[m][n], 0, 0, 0);
    __syncthreads();  // single barrier/K-step: publishes buf^1, fences cur reuse
  }

#pragma unroll
  for (int m = 0; m < 4; m++) {
    int row = m0 + wr + m * 16 + g * 4;
#pragma unroll
    for (int n = 0; n < 4; n++) {
      int col = n0 + wc + n * 16 + lr;
      float bs = bias0[col];
      float sc = (col < NXc) ? L2E : 1.0f;  // pre-scale q for exp2-softmax
#pragma unroll
      for (int jj = 0; jj < 4; jj++)
        Cb[(size_t)(row + jj) * 3072 + col] = f2bf((acc[m][n][jj] + bs) * sc);
    }
  }
}

// ---------------- GEMM1: out = [acat | q] @ wcatT^T + biases ----------------
// r21: M=64 x N=64 tile, grid (16,64) = 1024 blocks = 4 blocks/CU (16 waves/CU).
// r20 counters showed gemm1 latency-starved at 2 blocks/CU (Occ 17%, MfmaUtil 15%);
// the TLP lever (r7/r14 wins) is the best-evidenced fix. Staging lightens to
// 2 gloads/thread; LDS 16 KB; B re-reads double but stay L3-resident.
__global__ __launch_bounds__(256) void k_gemm1(
    const unsigned short* __restrict__ A, int lda,    // acat (k < 1024)
    const unsigned short* __restrict__ A2, int lda2,  // qkv cols 0..1023 (k >= 1024)
    const unsigned short* __restrict__ BT,            // [1024][2048]
    const float* __restrict__ bias0, const float* __restrict__ bias1,
    float* __restrict__ Cf) {
  constexpr int K = 2048, ksplit = 1024;
  __shared__ __align__(16) unsigned short As[2][64 * 32];   // 4 KB per buf
  __shared__ __align__(16) unsigned short Bs[2][64 * 32];
  const int nbx = gridDim.x, nby = gridDim.y;
  const int nwg = nbx * nby;
  int id = blockIdx.y * nbx + blockIdx.x;
  id = (id & 7) * (nwg >> 3) + (id >> 3);  // T1 XCD swizzle (1024 % 8 == 0)
  const int bx = id % nbx;
  const int by = id / nbx;
  const int m0 = by * 64;
  const int n0 = bx * 64;

  const int tid = threadIdx.x;
  const int lane = tid & 63;
  const int w = tid >> 6;
  const int wr = (w >> 1) * 32;   // wave quadrant: 32x32 output
  const int wc = (w & 1) * 32;
  const int g = lane >> 4, lr = lane & 15;
  const int arow = tid >> 2;      // staging row 0..63 (A and B share the pattern)
  const int acs = (tid & 3) ^ (arow & 3);  // pre-swizzled source granule
  f32x4 acc[2][2] = {};

  auto stage = [&](int k0, int buf) {
    const unsigned short* ap = (k0 < ksplit)
        ? A + (size_t)(m0 + arow) * lda + k0
        : A2 + (size_t)(m0 + arow) * lda2 + (k0 - ksplit);
    gload_lds16(ap + acs * 8, (void*)(&As[buf][0] + w * 512));
    gload_lds16(BT + (size_t)(n0 + arow) * K + k0 + acs * 8, (void*)(&Bs[buf][0] + w * 512));
  };

  stage(0, 0);
  __syncthreads();

  for (int k0 = 0; k0 < K; k0 += 32) {
    const int cur = (k0 >> 5) & 1;
    if (k0 + 32 < K) stage(k0 + 32, cur ^ 1);  // issue-early: drained at the barrier
    s16x8 af[2], bfr[2];
#pragma unroll
    for (int m = 0; m < 2; m++) {
      int row = wr + m * 16 + lr;
      af[m] = *(const s16x8*)((const char*)&As[cur][0] + row * 64 + ((g ^ (row & 3)) * 16));
    }
#pragma unroll
    for (int n = 0; n < 2; n++) {
      int row = wc + n * 16 + lr;
      bfr[n] = *(const s16x8*)((const char*)&Bs[cur][0] + row * 64 + ((g ^ (row & 3)) * 16));
    }
#pragma unroll
    for (int m = 0; m < 2; m++)
#pragma unroll
      for (int n = 0; n < 2; n++)
        acc[m][n] = __builtin_amdgcn_mfma_f32_16x16x32_bf16(af[m], bfr[n], acc[m][n], 0, 0, 0);
    __syncthreads();  // single barrier/K-step: publishes buf^1, fences cur reuse
  }

#pragma unroll
  for (int m = 0; m < 2; m++) {
    int row = m0 + wr + m * 16 + g * 4;
#pragma unroll
    for (int n = 0; n < 2; n++) {
      int col = n0 + wc + n * 16 + lr;
      float bs = bias0[col] + bias1[col];
#pragma unroll
      for (int jj = 0; jj < 4; jj++)
        Cf[(size_t)(row + jj) * NXc + col] = acc[m][n][jj] + bs;
    }
  }
}

// ---------------- flash attention v13: r16 + deferred lrow reduction (r20, frozen) ---
__global__ __launch_bounds__(256) void k_attn(
    const unsigned short* __restrict__ qkv,  // [4096][3072] bf16 (q*l2e | k | v)
    const float* __restrict__ adj,           // [2048][2048]
    const unsigned char* __restrict__ tm,    // [32][32] 64x64 tiles
    unsigned short* __restrict__ acat) {     // [4096][1024] bf16
  __shared__ __align__(16) unsigned short Kb[2][64 * 64];   // [kv][16B-gran ^ (kv&7)]
  __shared__ __align__(16) unsigned short Vt[2][64 * 72];   // row d: sigma-permuted kv
  __shared__ int s_kts[34];
  __shared__ unsigned char s_tmv[32];
  __shared__ int s_nkt;

  const int bid = blockIdx.x;
  const int qt = 31 - (bid >> 5);  // heavy-first
  const int bh = bid & 31;
  const int h = bh & 15;
  const int b = bh >> 4;
  const int q0 = qt * 64;
  const int tid = threadIdx.x;
  const int lane = tid & 63;
  const int w = tid >> 6;
  const int g = lane >> 4, lr = lane & 15;
  const int sc = tid & 7;
  const int sr = tid >> 3;  // 0..31
  const int kvp = 2 * sr;
  const int prp = (kvp & 32) | (((kvp >> 4) & 1) << 2) | ((kvp & 12) << 1) | (kvp & 3);

  // wave-parallel compacted active-tile list (clamped at [n] and [n+1] for 2-deep)
  if (w == 0) {
    int kt = lane & 31;
    unsigned char v = tm[qt * 32 + kt];
    bool act = (lane < 32) && (v != 0);
    unsigned long long mk = __ballot(act);
    int n = __popcll(mk);
    if (act) {
      int idx = __popcll(mk & ((1ull << lane) - 1));
      s_kts[idx] = kt;
      s_tmv[idx] = v;
      if (idx == n - 1) { s_kts[n] = kt; s_kts[n + 1] = kt; }
    }
    if (lane == 0) s_nkt = n;
  }

  // Q fragments (mfma B-operand: col=q=lr, k=8g+j)
  s16x8 qf0, qf1;
  {
    size_t base = (size_t)(b * Tc + q0 + w * 16 + lr) * 3072 + h * 64 + g * 8;
    qf0 = *(const s16x8*)(qkv + base);
    qf1 = *(const s16x8*)(qkv + base + 32);
  }
  f32x4 o[4] = {};
  float lrow = 0.f;  // lane-local partial; cross-lane reduced once in epilogue

  __syncthreads();  // s_kts visible
  const int nkt = s_nkt;
  if (nkt == 0) return;  // block-uniform

  const unsigned short* kbase = qkv + (size_t)(b * Tc) * 3072 + 1024 + h * 64;
  const unsigned short* vbase = kbase + 1024;

  const size_t koff0 = (size_t)sr * 3072 + (sc ^ (sr & 7)) * 8;
  const size_t koff1 = (size_t)(sr + 32) * 3072 + (sc ^ (sr & 7)) * 8;
  const int kd0 = w * 1024 + lane * 16;   // bytes
  const int kd1 = kd0 + 4096;
  const size_t voff0 = (size_t)kvp * 3072 + sc * 8;
  const size_t voff1 = (size_t)(kvp + 1) * 3072 + sc * 8;
  const int pcol = ((prp + sc * 8) & 63) * 2;

  s16x8 kA0, kA1, vA0, vA1;  // in-flight staging registers (2-deep pipeline)
  auto load_tile = [&](int kt) {
    const unsigned short* kb = kbase + (size_t)kt * 64 * 3072;
    const unsigned short* vb = vbase + (size_t)kt * 64 * 3072;
    kA0 = *(const s16x8*)(kb + koff0);
    kA1 = *(const s16x8*)(kb + koff1);
    vA0 = *(const s16x8*)(vb + voff0);
    vA1 = *(const s16x8*)(vb + voff1);
  };
  auto write_tile = [&](int buf) {
    *(s16x8*)((char*)&Kb[buf][0] + kd0) = kA0;
    *(s16x8*)((char*)&Kb[buf][0] + kd1) = kA1;
    char* vt = (char*)&Vt[buf][0];
#pragma unroll
    for (int j = 0; j < 8; j++) {
      int d = sc * 8 + j;
      uint32_t pk = (uint32_t)(unsigned short)vA0[j] |
                    ((uint32_t)(unsigned short)vA1[j] << 16);
      *(uint32_t*)(vt + d * 144 + pcol) = pk;
    }
  };

  // prologue: tile 0 -> LDS buf0; tile 1 loads left in flight (registers)
  load_tile(s_kts[0]);
  write_tile(0);
  load_tile(s_kts[1]);
  __syncthreads();

  for (int i = 0; i < nkt; i++) {
    const int cur = i & 1;
    const int kt = s_kts[i];
    const int tmv = s_tmv[i];
    const int kv0 = kt * 64;

    write_tile(cur ^ 1);       // tile i+1 (vmcnt wait lands here)
    load_tile(s_kts[i + 2]);   // tile i+2 into freed registers

    // compute tile i
    f32x4 s[4];
    __builtin_amdgcn_s_setprio(1);
#pragma unroll
    for (int n = 0; n < 4; n++) {
      int kvr = n * 16 + lr;
      const char* kr = (const char*)&Kb[cur][0] + kvr * 128;
      s16x8 a0 = *(const s16x8*)(kr + ((g ^ (kvr & 7)) * 16));
      s16x8 a1 = *(const s16x8*)(kr + (((4 + g) ^ (kvr & 7)) * 16));
      f32x4 z = {};
      z = __builtin_amdgcn_mfma_f32_16x16x32_bf16(a0, qf0, z, 0, 0, 0);
      s[n] = __builtin_amdgcn_mfma_f32_16x16x32_bf16(a1, qf1, z, 0, 0, 0);
    }
    __builtin_amdgcn_s_setprio(0);

    if (tmv != 2) {  // w = s*adj + NEG*(1-adj), exact for binary adj
      const float* arow = adj + (size_t)(q0 + w * 16 + lr) * Tc + kv0;
#pragma unroll
      for (int n = 0; n < 4; n++) {
        float4 a = *(const float4*)(arow + n * 16 + 4 * g);
        s[n][0] = a.x * s[n][0] + NEGC * (1.0f - a.x);
        s[n][1] = a.y * s[n][1] + NEGC * (1.0f - a.y);
        s[n][2] = a.z * s[n][2] + NEGC * (1.0f - a.z);
        s[n][3] = a.w * s[n][3] + NEGC * (1.0f - a.w);
      }
    }

    // ---- no-max softmax: P = exp2(s); lane-local partial sum only ----
    float ps0 = 0.f, ps1 = 0.f;
#pragma unroll
    for (int n = 0; n < 4; n++) {
      float p0 = exp2fast(s[n][0]), p1 = exp2fast(s[n][1]);
      float p2 = exp2fast(s[n][2]), p3 = exp2fast(s[n][3]);
      s[n][0] = p0; s[n][1] = p1; s[n][2] = p2; s[n][3] = p3;
      ps0 += (p0 + p1); ps1 += (p2 + p3);
    }
    lrow += ps0 + ps1;  // cross-lane hops deferred to epilogue (additive softmax)

    // ---- P stays in registers: sigma-renamed packs (no LDS roundtrip) ----
    u32x4 pw0, pw1;
    pw0.x = cvt_pk_bf16(s[0][0], s[0][1]);
    pw0.y = cvt_pk_bf16(s[0][2], s[0][3]);
    pw0.z = cvt_pk_bf16(s[1][0], s[1][1]);
    pw0.w = cvt_pk_bf16(s[1][2], s[1][3]);
    pw1.x = cvt_pk_bf16(s[2][0], s[2][1]);
    pw1.y = cvt_pk_bf16(s[2][2], s[2][3]);
    pw1.z = cvt_pk_bf16(s[3][0], s[3][1]);
    pw1.w = cvt_pk_bf16(s[3][2], s[3][3]);
    s16x8 pa0 = __builtin_bit_cast(s16x8, pw0);
    s16x8 pa1 = __builtin_bit_cast(s16x8, pw1);

    __builtin_amdgcn_s_setprio(1);
#pragma unroll
    for (int nd = 0; nd < 4; nd++) {
      int d = nd * 16 + lr;
      const char* vrow = (const char*)&Vt[cur][0] + d * 144;
      int swz = (d >> 3) * 8;
      s16x8 vb0 = *(const s16x8*)(vrow + (((8 * g + swz) & 63) * 2));
      s16x8 vb1 = *(const s16x8*)(vrow + (((32 + 8 * g + swz) & 63) * 2));
      o[nd] = __builtin_amdgcn_mfma_f32_16x16x32_bf16(pa0, vb0, o[nd], 0, 0, 0);
      o[nd] = __builtin_amdgcn_mfma_f32_16x16x32_bf16(pa1, vb1, o[nd], 0, 0, 0);
    }
    __builtin_amdgcn_s_setprio(0);

    __syncthreads();  // single barrier/tile: publishes buf^1, fences cur reuse
  }

  // epilogue: complete the deferred cross-lane row-sum (2 hops total, not 2/tile)
  lrow += __shfl_xor(lrow, 16);
  lrow += __shfl_xor(lrow, 32);
  float inv = lrow > 0.f ? 1.0f / lrow : 0.f;
#pragma unroll
  for (int jj = 0; jj < 4; jj++) {
    float iv = __shfl(inv, 4 * g + jj);
    size_t m = (size_t)(b * Tc + q0 + w * 16 + g * 4 + jj);
#pragma unroll
    for (int nd = 0; nd < 4; nd++)
      acat[m * 1024 + h * 64 + nd * 16 + lr] = f2bf(o[nd][jj] * iv);
  }
}

extern "C" void kernel_launch(void* const* d_in, const int* in_sizes, int n_in,
                              void* d_out, int out_size, void* d_ws, size_t ws_size,
                              hipStream_t stream) {
  const float* x       = (const float*)d_in[0];
  const float* adj     = (const float*)d_in[1];
  const float* w_attn  = (const float*)d_in[2];
  const float* b_attn  = (const float*)d_in[3];
  const float* w_proj  = (const float*)d_in[4];
  const float* b_proj  = (const float*)d_in[5];
  const float* w_proj1 = (const float*)d_in[6];
  const float* b_proj1 = (const float*)d_in[7];
  float* out = (float*)d_out;

  char* ws = (char*)d_ws;
  size_t off = 0;
  unsigned short* xb     = (unsigned short*)(ws + off); off += (size_t)4096 * 1024 * 2;
  unsigned short* wattnT = (unsigned short*)(ws + off); off += (size_t)3072 * 1024 * 2;
  unsigned short* wcatT  = (unsigned short*)(ws + off); off += (size_t)1024 * 2048 * 2;
  unsigned short* qkv    = (unsigned short*)(ws + off); off += (size_t)4096 * 3072 * 2;
  unsigned short* acat   = (unsigned short*)(ws + off); off += (size_t)4096 * 1024 * 2;
  unsigned char*  tmask  = (unsigned char*)(ws + off);  off += 1024;
  (void)ws_size; (void)in_sizes; (void)n_in; (void)out_size;

  // all prep in one dispatch (cvt_x | w_attn^T | w_proj^T | w_proj1^T*ln2 | tilemask)
  k_prep<<<10240, 256, 0, stream>>>(x, xb, w_attn, wattnT, w_proj, w_proj1, wcatT,
                                    adj, tmask);
  // qkv = x @ w_attn + b_attn (q columns scaled by log2e in epilogue)
  k_gemm0<<<dim3(24, 32), 256, 0, stream>>>(xb, 1024, wattnT, 1024, b_attn, qkv);
  // attention -> acat [4096][1024]
  k_attn<<<1024, 256, 0, stream>>>(qkv, adj, tmask, acat);
  // out = [a | q*l2e] @ [w_proj ; w_proj1*ln2] + biases (64x64 tile, 1024 blocks)
  k_gemm1<<<dim3(16, 64), 256, 0, stream>>>(acat, 1024, qkv, 3072,
                                            wcatT, b_proj, b_proj1, out);
}

// Round 22
// 118.587 us; speedup vs baseline: 1.0602x; 1.0602x over previous
//
#include <hip/hip_runtime.h>
#include <stdint.h>

typedef short s16x8 __attribute__((ext_vector_type(8)));
typedef float f32x4 __attribute__((ext_vector_type(4)));
typedef unsigned int u32x4 __attribute__((ext_vector_type(4)));

#define AS1 __attribute__((address_space(1)))
#define AS3 __attribute__((address_space(3)))

static constexpr int Bc = 2, Tc = 2048, NXc = 1024, Hc = 16;
static constexpr float NEGC = -1e9f;
static constexpr float L2E = 1.44269504088896340736f;  // log2(e)
static constexpr float LN2 = 0.69314718055994530942f;  // 1/log2(e)

static __device__ __forceinline__ unsigned short f2bf(float f) {
  uint32_t u = __builtin_bit_cast(uint32_t, f);
  u += 0x7fffu + ((u >> 16) & 1u);
  return (unsigned short)(u >> 16);
}

static __device__ __forceinline__ float exp2fast(float x) {
  return __builtin_amdgcn_exp2f(x);  // v_exp_f32: D = 2^S0
}

static __device__ __forceinline__ uint32_t cvt_pk_bf16(float lo, float hi) {
  uint32_t r;
  asm("v_cvt_pk_bf16_f32 %0, %1, %2" : "=v"(r) : "v"(lo), "v"(hi));
  return r;
}

static __device__ __forceinline__ void gload_lds16(const void* g, void* l) {
  __builtin_amdgcn_global_load_lds((const AS1 uint32_t*)g, (AS3 uint32_t*)l, 16, 0, 0);
}

// ---------------- fused prep: cvt_x | 3 transposes | tilemask(64x64) ----------------
__global__ __launch_bounds__(256) void k_prep(
    const float* __restrict__ x, unsigned short* __restrict__ xb,
    const float* __restrict__ w_attn, unsigned short* __restrict__ wattnT,
    const float* __restrict__ w_proj, const float* __restrict__ w_proj1,
    unsigned short* __restrict__ wcatT,
    const float* __restrict__ adj, unsigned char* __restrict__ tm) {
  __shared__ float tile[32][33];
  __shared__ int s_any, s_all;
  const int bid = blockIdx.x;
  const int t = threadIdx.x;

  if (bid < 4096) {  // x -> bf16
    int i = bid * 256 + t;
    float4 v = ((const float4*)x)[i];
    uint32_t lo = (uint32_t)f2bf(v.x) | ((uint32_t)f2bf(v.y) << 16);
    uint32_t hi = (uint32_t)f2bf(v.z) | ((uint32_t)f2bf(v.w) << 16);
    ((uint2*)xb)[i] = make_uint2(lo, hi);
    return;
  }
  if (bid < 9216) {  // f32 [K][N] -> bf16 [N][dld] transposes
    const float* src; unsigned short* dst;
    int scols, dld, dkoff, n0, k0; float scale;
    if (bid < 7168) {
      int b = bid - 4096; n0 = (b % 96) * 32; k0 = (b / 96) * 32;
      src = w_attn; scols = 3072; dst = wattnT; dld = 1024; dkoff = 0; scale = 1.0f;
    } else if (bid < 8192) {
      int b = bid - 7168; n0 = (b & 31) * 32; k0 = (b >> 5) * 32;
      src = w_proj; scols = 1024; dst = wcatT; dld = 2048; dkoff = 0; scale = 1.0f;
    } else {
      int b = bid - 8192; n0 = (b & 31) * 32; k0 = (b >> 5) * 32;
      // w_proj1 pre-scaled by ln2 cancels the log2e baked into q (exp2 rebasing)
      src = w_proj1; scols = 1024; dst = wcatT; dld = 2048; dkoff = 1024; scale = LN2;
    }
    int tx = t & 31, ty = t >> 5;
#pragma unroll
    for (int r = 0; r < 4; r++)
      tile[ty + r * 8][tx] = src[(size_t)(k0 + ty + r * 8) * scols + n0 + tx];
    __syncthreads();
#pragma unroll
    for (int r = 0; r < 4; r++) {
      int n = n0 + ty + r * 8;
      dst[(size_t)n * dld + dkoff + k0 + tx] = f2bf(tile[tx][ty + r * 8] * scale);
    }
    return;
  }
  {  // adjacency 64x64 tile classifier: 0=skip, 1=mixed, 2=all-ones
    int b = bid - 9216;
    int kt = b & 31, qt = b >> 5;
    bool anyv = false, all1 = true;
#pragma unroll
    for (int i = 0; i < 4; i++) {
      int e = t * 4 + i;
      int row = e >> 4, c4 = e & 15;
      float4 v = *(const float4*)&adj[(size_t)(qt * 64 + row) * Tc + kt * 64 + c4 * 4];
      anyv |= (v.x != 0.f) | (v.y != 0.f) | (v.z != 0.f) | (v.w != 0.f);
      all1 &= (v.x == 1.f) & (v.y == 1.f) & (v.z == 1.f) & (v.w == 1.f);
    }
    if (t == 0) { s_any = 0; s_all = 1; }
    __syncthreads();
    if (anyv) s_any = 1;
    if (!all1) s_all = 0;
    __syncthreads();
    if (t == 0) tm[qt * 32 + kt] = (unsigned char)(s_any ? (s_all ? 2 : 1) : 0);
  }
}

// ---------------- GEMM0: qkv = xb @ wattnT^T + b_attn (single-barrier dbuf, r19) -----
__global__ __launch_bounds__(256) void k_gemm0(
    const unsigned short* __restrict__ A, int lda,
    const unsigned short* __restrict__ BT, int K,
    const float* __restrict__ bias0, unsigned short* __restrict__ Cb) {
  __shared__ __align__(16) unsigned short As[2][128 * 32];
  __shared__ __align__(16) unsigned short Bs[2][128 * 32];
  const int nbx = gridDim.x, nby = gridDim.y;
  const int nwg = nbx * nby;
  int id = blockIdx.y * nbx + blockIdx.x;
  id = (id & 7) * (nwg >> 3) + (id >> 3);  // T1 XCD swizzle (nwg % 8 == 0)
  const int bx = id % nbx;
  const int by = id / nbx;
  const int m0 = by * 128;
  const int n0 = bx * 128;

  const int lane = threadIdx.x & 63;
  const int w = threadIdx.x >> 6;
  const int wr = (w >> 1) * 64;
  const int wc = (w & 1) * 64;
  const int g = lane >> 4, lr = lane & 15;
  const int srow = lane >> 2;
  const int scol = lane & 3;
  f32x4 acc[4][4] = {};

  auto stage = [&](int k0, int buf) {
#pragma unroll
    for (int i = 0; i < 2; i++) {
      int c = w * 2 + i;
      int row = c * 16 + srow;
      int cs = scol ^ (row & 3);
      gload_lds16(A + (size_t)(m0 + row) * lda + k0 + cs * 8, (void*)(&As[buf][0] + c * 512));
      gload_lds16(BT + (size_t)(n0 + row) * K + k0 + cs * 8, (void*)(&Bs[buf][0] + c * 512));
    }
  };

  stage(0, 0);
  __syncthreads();

  for (int k0 = 0; k0 < K; k0 += 32) {
    const int cur = (k0 >> 5) & 1;
    if (k0 + 32 < K) stage(k0 + 32, cur ^ 1);  // issue-early: drained at the barrier
    s16x8 af[4], bfr[4];
#pragma unroll
    for (int m = 0; m < 4; m++) {
      int row = wr + m * 16 + lr;
      af[m] = *(const s16x8*)((const char*)&As[cur][0] + row * 64 + ((g ^ (row & 3)) * 16));
    }
#pragma unroll
    for (int n = 0; n < 4; n++) {
      int row = wc + n * 16 + lr;
      bfr[n] = *(const s16x8*)((const char*)&Bs[cur][0] + row * 64 + ((g ^ (row & 3)) * 16));
    }
#pragma unroll
    for (int m = 0; m < 4; m++)
#pragma unroll
      for (int n = 0; n < 4; n++)
        acc[m][n] = __builtin_amdgcn_mfma_f32_16x16x32_bf16(af[m], bfr[n], acc[m][n], 0, 0, 0);
    __syncthreads();  // single barrier/K-step: publishes buf^1, fences cur reuse
  }

#pragma unroll
  for (int m = 0; m < 4; m++) {
    int row = m0 + wr + m * 16 + g * 4;
#pragma unroll
    for (int n = 0; n < 4; n++) {
      int col = n0 + wc + n * 16 + lr;
      float bs = bias0[col];
      float sc = (col < NXc) ? L2E : 1.0f;  // pre-scale q for exp2-softmax
#pragma unroll
      for (int jj = 0; jj < 4; jj++)
        Cb[(size_t)(row + jj) * 3072 + col] = f2bf((acc[m][n][jj] + bs) * sc);
    }
  }
}

// ---------------- GEMM1: out = [acat | q] @ wcatT^T + biases ----------------
// r22: M=64 x N=128 (r20 shape, 512 blocks) + r16's 2-deep REGISTER-staged pipeline.
// r21 post-mortem eliminated occupancy as gemm1's limiter; the remaining stall is the
// vmcnt(0) drain at the barrier (cover = 1 K-step). Reg staging moves the wait to the
// ds_write one full iteration after issue; barrier waits only on lgkm. 3 loads/thread.
__global__ __launch_bounds__(256) void k_gemm1(
    const unsigned short* __restrict__ A, int lda,    // acat (k < 1024)
    const unsigned short* __restrict__ A2, int lda2,  // qkv cols 0..1023 (k >= 1024)
    const unsigned short* __restrict__ BT,            // [1024][2048]
    const float* __restrict__ bias0, const float* __restrict__ bias1,
    float* __restrict__ Cf) {
  constexpr int K = 2048, ksplit = 1024;
  __shared__ __align__(16) unsigned short As[2][64 * 32];    // 8 KB dbuf
  __shared__ __align__(16) unsigned short Bs[2][128 * 32];   // 16 KB dbuf
  const int nbx = gridDim.x, nby = gridDim.y;
  const int nwg = nbx * nby;
  int id = blockIdx.y * nbx + blockIdx.x;
  id = (id & 7) * (nwg >> 3) + (id >> 3);  // T1 XCD swizzle (512 % 8 == 0)
  const int bx = id % nbx;
  const int by = id / nbx;
  const int m0 = by * 64;
  const int n0 = bx * 128;

  const int tid = threadIdx.x;
  const int lane = tid & 63;
  const int w = tid >> 6;
  const int wr = (w >> 1) * 32;
  const int wc = (w & 1) * 64;
  const int g = lane >> 4, lr = lane & 15;
  const int srow = lane >> 2;
  const int scol = lane & 3;
  const int arow = tid >> 2;                 // A staging row 0..63
  const int acs = (tid & 3) ^ (arow & 3);    // pre-swizzled source granule (A)
  // B staging rows: c = 2w+i, row = c*16+srow, granule cs = scol ^ (row&3)
  const int brow0 = (w * 2) * 16 + srow, brow1 = (w * 2 + 1) * 16 + srow;
  const int bcs0 = scol ^ (brow0 & 3), bcs1 = scol ^ (brow1 & 3);
  const size_t boff0 = (size_t)(n0 + brow0) * K + bcs0 * 8;
  const size_t boff1 = (size_t)(n0 + brow1) * K + bcs1 * 8;
  // linear LDS dests (byte-identical to the gload_lds image)
  const int ad = w * 1024 + lane * 16;
  const int bd0 = (w * 2) * 1024 + lane * 16;
  const int bd1 = (w * 2 + 1) * 1024 + lane * 16;

  s16x8 aR, bR0, bR1;  // in-flight staging registers (2-deep pipeline)
  auto load_t = [&](int k0) {
    const unsigned short* ap = (k0 < ksplit)
        ? A + (size_t)(m0 + arow) * lda + k0
        : A2 + (size_t)(m0 + arow) * lda2 + (k0 - ksplit);
    aR  = *(const s16x8*)(ap + acs * 8);
    bR0 = *(const s16x8*)(BT + boff0 + k0);
    bR1 = *(const s16x8*)(BT + boff1 + k0);
  };
  auto write_t = [&](int buf) {
    *(s16x8*)((char*)&As[buf][0] + ad)  = aR;
    *(s16x8*)((char*)&Bs[buf][0] + bd0) = bR0;
    *(s16x8*)((char*)&Bs[buf][0] + bd1) = bR1;
  };

  f32x4 acc[2][4] = {};

  // prologue: tile 0 -> LDS buf0; tile 1 loads left in flight (registers)
  load_t(0);
  write_t(0);
  load_t(32);
  __syncthreads();

  for (int k0 = 0; k0 < K; k0 += 32) {
    const int cur = (k0 >> 5) & 1;
    write_t(cur ^ 1);               // tile k0+32 (vmcnt wait lands here, 1 iter late)
    load_t(min(k0 + 64, K - 32));   // tile k0+64 (clamped; tail writes are dead)
    s16x8 af[2], bfr[4];
#pragma unroll
    for (int m = 0; m < 2; m++) {
      int row = wr + m * 16 + lr;
      af[m] = *(const s16x8*)((const char*)&As[cur][0] + row * 64 + ((g ^ (row & 3)) * 16));
    }
#pragma unroll
    for (int n = 0; n < 4; n++) {
      int row = wc + n * 16 + lr;
      bfr[n] = *(const s16x8*)((const char*)&Bs[cur][0] + row * 64 + ((g ^ (row & 3)) * 16));
    }
#pragma unroll
    for (int m = 0; m < 2; m++)
#pragma unroll
      for (int n = 0; n < 4; n++)
        acc[m][n] = __builtin_amdgcn_mfma_f32_16x16x32_bf16(af[m], bfr[n], acc[m][n], 0, 0, 0);
    __syncthreads();  // single barrier/K-step (lgkm only; no global drain)
  }

#pragma unroll
  for (int m = 0; m < 2; m++) {
    int row = m0 + wr + m * 16 + g * 4;
#pragma unroll
    for (int n = 0; n < 4; n++) {
      int col = n0 + wc + n * 16 + lr;
      float bs = bias0[col] + bias1[col];
#pragma unroll
      for (int jj = 0; jj < 4; jj++)
        Cf[(size_t)(row + jj) * NXc + col] = acc[m][n][jj] + bs;
    }
  }
}

// ---------------- flash attention v13: r16 + deferred lrow reduction (r20, frozen) ---
__global__ __launch_bounds__(256) void k_attn(
    const unsigned short* __restrict__ qkv,  // [4096][3072] bf16 (q*l2e | k | v)
    const float* __restrict__ adj,           // [2048][2048]
    const unsigned char* __restrict__ tm,    // [32][32] 64x64 tiles
    unsigned short* __restrict__ acat) {     // [4096][1024] bf16
  __shared__ __align__(16) unsigned short Kb[2][64 * 64];   // [kv][16B-gran ^ (kv&7)]
  __shared__ __align__(16) unsigned short Vt[2][64 * 72];   // row d: sigma-permuted kv
  __shared__ int s_kts[34];
  __shared__ unsigned char s_tmv[32];
  __shared__ int s_nkt;

  const int bid = blockIdx.x;
  const int qt = 31 - (bid >> 5);  // heavy-first
  const int bh = bid & 31;
  const int h = bh & 15;
  const int b = bh >> 4;
  const int q0 = qt * 64;
  const int tid = threadIdx.x;
  const int lane = tid & 63;
  const int w = tid >> 6;
  const int g = lane >> 4, lr = lane & 15;
  const int sc = tid & 7;
  const int sr = tid >> 3;  // 0..31
  const int kvp = 2 * sr;
  const int prp = (kvp & 32) | (((kvp >> 4) & 1) << 2) | ((kvp & 12) << 1) | (kvp & 3);

  // wave-parallel compacted active-tile list (clamped at [n] and [n+1] for 2-deep)
  if (w == 0) {
    int kt = lane & 31;
    unsigned char v = tm[qt * 32 + kt];
    bool act = (lane < 32) && (v != 0);
    unsigned long long mk = __ballot(act);
    int n = __popcll(mk);
    if (act) {
      int idx = __popcll(mk & ((1ull << lane) - 1));
      s_kts[idx] = kt;
      s_tmv[idx] = v;
      if (idx == n - 1) { s_kts[n] = kt; s_kts[n + 1] = kt; }
    }
    if (lane == 0) s_nkt = n;
  }

  // Q fragments (mfma B-operand: col=q=lr, k=8g+j)
  s16x8 qf0, qf1;
  {
    size_t base = (size_t)(b * Tc + q0 + w * 16 + lr) * 3072 + h * 64 + g * 8;
    qf0 = *(const s16x8*)(qkv + base);
    qf1 = *(const s16x8*)(qkv + base + 32);
  }
  f32x4 o[4] = {};
  float lrow = 0.f;  // lane-local partial; cross-lane reduced once in epilogue

  __syncthreads();  // s_kts visible
  const int nkt = s_nkt;
  if (nkt == 0) return;  // block-uniform

  const unsigned short* kbase = qkv + (size_t)(b * Tc) * 3072 + 1024 + h * 64;
  const unsigned short* vbase = kbase + 1024;

  const size_t koff0 = (size_t)sr * 3072 + (sc ^ (sr & 7)) * 8;
  const size_t koff1 = (size_t)(sr + 32) * 3072 + (sc ^ (sr & 7)) * 8;
  const int kd0 = w * 1024 + lane * 16;   // bytes
  const int kd1 = kd0 + 4096;
  const size_t voff0 = (size_t)kvp * 3072 + sc * 8;
  const size_t voff1 = (size_t)(kvp + 1) * 3072 + sc * 8;
  const int pcol = ((prp + sc * 8) & 63) * 2;

  s16x8 kA0, kA1, vA0, vA1;  // in-flight staging registers (2-deep pipeline)
  auto load_tile = [&](int kt) {
    const unsigned short* kb = kbase + (size_t)kt * 64 * 3072;
    const unsigned short* vb = vbase + (size_t)kt * 64 * 3072;
    kA0 = *(const s16x8*)(kb + koff0);
    kA1 = *(const s16x8*)(kb + koff1);
    vA0 = *(const s16x8*)(vb + voff0);
    vA1 = *(const s16x8*)(vb + voff1);
  };
  auto write_tile = [&](int buf) {
    *(s16x8*)((char*)&Kb[buf][0] + kd0) = kA0;
    *(s16x8*)((char*)&Kb[buf][0] + kd1) = kA1;
    char* vt = (char*)&Vt[buf][0];
#pragma unroll
    for (int j = 0; j < 8; j++) {
      int d = sc * 8 + j;
      uint32_t pk = (uint32_t)(unsigned short)vA0[j] |
                    ((uint32_t)(unsigned short)vA1[j] << 16);
      *(uint32_t*)(vt + d * 144 + pcol) = pk;
    }
  };

  // prologue: tile 0 -> LDS buf0; tile 1 loads left in flight (registers)
  load_tile(s_kts[0]);
  write_tile(0);
  load_tile(s_kts[1]);
  __syncthreads();

  for (int i = 0; i < nkt; i++) {
    const int cur = i & 1;
    const int kt = s_kts[i];
    const int tmv = s_tmv[i];
    const int kv0 = kt * 64;

    write_tile(cur ^ 1);       // tile i+1 (vmcnt wait lands here)
    load_tile(s_kts[i + 2]);   // tile i+2 into freed registers

    // compute tile i
    f32x4 s[4];
    __builtin_amdgcn_s_setprio(1);
#pragma unroll
    for (int n = 0; n < 4; n++) {
      int kvr = n * 16 + lr;
      const char* kr = (const char*)&Kb[cur][0] + kvr * 128;
      s16x8 a0 = *(const s16x8*)(kr + ((g ^ (kvr & 7)) * 16));
      s16x8 a1 = *(const s16x8*)(kr + (((4 + g) ^ (kvr & 7)) * 16));
      f32x4 z = {};
      z = __builtin_amdgcn_mfma_f32_16x16x32_bf16(a0, qf0, z, 0, 0, 0);
      s[n] = __builtin_amdgcn_mfma_f32_16x16x32_bf16(a1, qf1, z, 0, 0, 0);
    }
    __builtin_amdgcn_s_setprio(0);

    if (tmv != 2) {  // w = s*adj + NEG*(1-adj), exact for binary adj
      const float* arow = adj + (size_t)(q0 + w * 16 + lr) * Tc + kv0;
#pragma unroll
      for (int n = 0; n < 4; n++) {
        float4 a = *(const float4*)(arow + n * 16 + 4 * g);
        s[n][0] = a.x * s[n][0] + NEGC * (1.0f - a.x);
        s[n][1] = a.y * s[n][1] + NEGC * (1.0f - a.y);
        s[n][2] = a.z * s[n][2] + NEGC * (1.0f - a.z);
        s[n][3] = a.w * s[n][3] + NEGC * (1.0f - a.w);
      }
    }

    // ---- no-max softmax: P = exp2(s); lane-local partial sum only ----
    float ps0 = 0.f, ps1 = 0.f;
#pragma unroll
    for (int n = 0; n < 4; n++) {
      float p0 = exp2fast(s[n][0]), p1 = exp2fast(s[n][1]);
      float p2 = exp2fast(s[n][2]), p3 = exp2fast(s[n][3]);
      s[n][0] = p0; s[n][1] = p1; s[n][2] = p2; s[n][3] = p3;
      ps0 += (p0 + p1); ps1 += (p2 + p3);
    }
    lrow += ps0 + ps1;  // cross-lane hops deferred to epilogue (additive softmax)

    // ---- P stays in registers: sigma-renamed packs (no LDS roundtrip) ----
    u32x4 pw0, pw1;
    pw0.x = cvt_pk_bf16(s[0][0], s[0][1]);
    pw0.y = cvt_pk_bf16(s[0][2], s[0][3]);
    pw0.z = cvt_pk_bf16(s[1][0], s[1][1]);
    pw0.w = cvt_pk_bf16(s[1][2], s[1][3]);
    pw1.x = cvt_pk_bf16(s[2][0], s[2][1]);
    pw1.y = cvt_pk_bf16(s[2][2], s[2][3]);
    pw1.z = cvt_pk_bf16(s[3][0], s[3][1]);
    pw1.w = cvt_pk_bf16(s[3][2], s[3][3]);
    s16x8 pa0 = __builtin_bit_cast(s16x8, pw0);
    s16x8 pa1 = __builtin_bit_cast(s16x8, pw1);

    __builtin_amdgcn_s_setprio(1);
#pragma unroll
    for (int nd = 0; nd < 4; nd++) {
      int d = nd * 16 + lr;
      const char* vrow = (const char*)&Vt[cur][0] + d * 144;
      int swz = (d >> 3) * 8;
      s16x8 vb0 = *(const s16x8*)(vrow + (((8 * g + swz) & 63) * 2));
      s16x8 vb1 = *(const s16x8*)(vrow + (((32 + 8 * g + swz) & 63) * 2));
      o[nd] = __builtin_amdgcn_mfma_f32_16x16x32_bf16(pa0, vb0, o[nd], 0, 0, 0);
      o[nd] = __builtin_amdgcn_mfma_f32_16x16x32_bf16(pa1, vb1, o[nd], 0, 0, 0);
    }
    __builtin_amdgcn_s_setprio(0);

    __syncthreads();  // single barrier/tile: publishes buf^1, fences cur reuse
  }

  // epilogue: complete the deferred cross-lane row-sum (2 hops total, not 2/tile)
  lrow += __shfl_xor(lrow, 16);
  lrow += __shfl_xor(lrow, 32);
  float inv = lrow > 0.f ? 1.0f / lrow : 0.f;
#pragma unroll
  for (int jj = 0; jj < 4; jj++) {
    float iv = __shfl(inv, 4 * g + jj);
    size_t m = (size_t)(b * Tc + q0 + w * 16 + g * 4 + jj);
#pragma unroll
    for (int nd = 0; nd < 4; nd++)
      acat[m * 1024 + h * 64 + nd * 16 + lr] = f2bf(o[nd][jj] * iv);
  }
}

extern "C" void kernel_launch(void* const* d_in, const int* in_sizes, int n_in,
                              void* d_out, int out_size, void* d_ws, size_t ws_size,
                              hipStream_t stream) {
  const float* x       = (const float*)d_in[0];
  const float* adj     = (const float*)d_in[1];
  const float* w_attn  = (const float*)d_in[2];
  const float* b_attn  = (const float*)d_in[3];
  const float* w_proj  = (const float*)d_in[4];
  const float* b_proj  = (const float*)d_in[5];
  const float* w_proj1 = (const float*)d_in[6];
  const float* b_proj1 = (const float*)d_in[7];
  float* out = (float*)d_out;

  char* ws = (char*)d_ws;
  size_t off = 0;
  unsigned short* xb     = (unsigned short*)(ws + off); off += (size_t)4096 * 1024 * 2;
  unsigned short* wattnT = (unsigned short*)(ws + off); off += (size_t)3072 * 1024 * 2;
  unsigned short* wcatT  = (unsigned short*)(ws + off); off += (size_t)1024 * 2048 * 2;
  unsigned short* qkv    = (unsigned short*)(ws + off); off += (size_t)4096 * 3072 * 2;
  unsigned short* acat   = (unsigned short*)(ws + off); off += (size_t)4096 * 1024 * 2;
  unsigned char*  tmask  = (unsigned char*)(ws + off);  off += 1024;
  (void)ws_size; (void)in_sizes; (void)n_in; (void)out_size;

  // all prep in one dispatch (cvt_x | w_attn^T | w_proj^T | w_proj1^T*ln2 | tilemask)
  k_prep<<<10240, 256, 0, stream>>>(x, xb, w_attn, wattnT, w_proj, w_proj1, wcatT,
                                    adj, tmask);
  // qkv = x @ w_attn + b_attn (q columns scaled by log2e in epilogue)
  k_gemm0<<<dim3(24, 32), 256, 0, stream>>>(xb, 1024, wattnT, 1024, b_attn, qkv);
  // attention -> acat [4096][1024]
  k_attn<<<1024, 256, 0, stream>>>(qkv, adj, tmask, acat);
  // out = [a | q*l2e] @ [w_proj ; w_proj1*ln2] + biases (M=64xN=128, reg-staged 2-deep)
  k_gemm1<<<dim3(8, 64), 256, 0, stream>>>(acat, 1024, qkv, 3072,
                                           wcatT, b_proj, b_proj1, out);
}